// Round 13
// baseline (312.592 us; speedup 1.0000x reference)
//
#include <hip/hip_runtime.h>
#include <hip/hip_fp16.h>
#include <math.h>

#define Bb 64
#define Nn 1000
#define Gg 500
#define Hh 256
#define GP 512
#define NP 1024

// float offsets into d_ws (total 22,151,168 floats = 88.6 MB)
#define WS_MP   0u           // [B][H][16] fp32 column-sum partials
#define WS_BM   262144u      // u16 [B][GP][64] visited bitmask
#define WS_WC16 1310720u     // u16 [256][512] Wcat fp16
#define WS_E16  1376256u     // u16 [B][N][H] emb fp16 row-major
#define WS_T16  9568256u     // u16 [B][H][NP] embT fp16 (dead after k_pool)
#define WS_P16  17956864u    // u16 [B][GP][H] pooled fp16 (dead after k_finalq)
#define WS_F16  WS_T16       // u16 [B][GP][H] fq fp16 (overlays T16)

typedef __attribute__((ext_vector_type(8))) short short8;
typedef __attribute__((ext_vector_type(8))) _Float16 f16x8;
typedef __attribute__((ext_vector_type(4))) float f32x4;
typedef __attribute__((ext_vector_type(4))) unsigned short u16x4;

#define MFMAH(a,b,c) __builtin_amdgcn_mfma_f32_16x16x32_f16(a,b,c,0,0,0)
// swizzled LDS offset (shorts): 64-short rows, 8 chunks of 8 halves (16B)
#define SW(row, chunk) (((row) << 6) + ((((chunk) ^ ((row) & 7))) << 3))

__device__ __forceinline__ unsigned short f16b(float v) {
  return __half_as_ushort(__float2half(v));
}
__device__ __forceinline__ float h2f(unsigned short u) {
  return __half2float(__ushort_as_half(u));
}

// ---------------- front: prep (bid<4096) + bm (4096..12287) + wcat ----------
__global__ __launch_bounds__(256) void k_front(const float* __restrict__ emb,
                                               const float* __restrict__ gm,
                                               const float* __restrict__ Wf,
                                               const float* __restrict__ Wl,
                                               const float* __restrict__ Wv,
                                               float* __restrict__ ws) {
  __shared__ float tile[64][68];
  __shared__ float colsum[16][64];
  int bid = blockIdx.x, t = threadIdx.x;
  if (bid < 4096) {
    // ---- prep: emb -> e16 + t16 + column-sum partials ----
    int nt = bid & 15, ht = (bid >> 4) & 3, b = bid >> 6;
    int c4 = (t & 15) * 4, r0 = t >> 4;
    int n0 = nt * 64, h0 = ht * 64;
    unsigned short* e16 = (unsigned short*)(ws + WS_E16);
    unsigned short* t16 = (unsigned short*)(ws + WS_T16);
    float cs0 = 0.f, cs1 = 0.f, cs2 = 0.f, cs3 = 0.f;
#pragma unroll
    for (int rr = 0; rr < 4; ++rr) {
      int r = r0 + rr * 16;
      int n = n0 + r;
      float4 v = {0.f, 0.f, 0.f, 0.f};
      if (n < Nn) {
        size_t idx = ((size_t)(b * Nn + n)) * Hh + h0 + c4;
        v = *(const float4*)(emb + idx);
        u16x4 e4 = { f16b(v.x), f16b(v.y), f16b(v.z), f16b(v.w) };
        *(u16x4*)(e16 + idx) = e4;
      }
      *(float4*)&tile[r][c4] = v;
      cs0 += v.x; cs1 += v.y; cs2 += v.z; cs3 += v.w;
    }
    colsum[r0][c4 + 0] = cs0; colsum[r0][c4 + 1] = cs1;
    colsum[r0][c4 + 2] = cs2; colsum[r0][c4 + 3] = cs3;
    __syncthreads();
    {
      int h_l = t >> 2, nseg = t & 3;
      short8 h8a, h8b;
#pragma unroll
      for (int i = 0; i < 16; ++i) {
        float v = tile[nseg * 16 + i][h_l];
        unsigned short hv = f16b(v);
        if (i < 8) h8a[i] = (short)hv;
        else       h8b[i-8] = (short)hv;
      }
      size_t base = ((size_t)(b * Hh + h0 + h_l)) * NP + n0 + nseg * 16;
      *(short8*)(t16 + base) = h8a; *(short8*)(t16 + base + 8) = h8b;
    }
    if (t < 64) {
      float s = 0.f;
#pragma unroll
      for (int i = 0; i < 16; ++i) s += colsum[i][t];
      ws[WS_MP + (((size_t)(b * Hh + h0 + t)) << 4) + nt] = s;
    }
  } else if (bid < 12288) {
    // ---- bm: gm -> bitmask ----
    int w = t >> 6, l = t & 63;
    int row = (bid - 4096) * 4 + w;          // b*GP + g
    int b = row >> 9, g = row & 511;
    unsigned long long* dst = (unsigned long long*)((unsigned short*)(ws + WS_BM) + (size_t)row * 64);
    if (g < Gg) {
      const float* src = gm + ((size_t)b * Gg + g) * Nn;
#pragma unroll
      for (int i = 0; i < 16; ++i) {
        int n = i * 64 + l;
        bool bit = (n < Nn) ? (src[n] < -1e30f) : false;
        unsigned long long m = __ballot(bit);
        if (l == i) dst[i] = m;
      }
    } else {
      if (l < 16) dst[l] = 0ull;
    }
  } else {
    // ---- wcat fp16 ----
    int o = bid - 12288, k = t;
    unsigned short* wc = (unsigned short*)(ws + WS_WC16);
    wc[o*512 + k]       = f16b(Wv[o*Hh + k]);
    wc[o*512 + 256 + k] = f16b(Wl[o*Hh + k] + Wf[o*Hh + k]);
  }
}

// ---------------- pool GEMM: pooled[g][h] = (1/N) mask @ emb ----------------
// grid(ht=2, gt=4, b=64), block(256)=2x2 waves, wave tile 64h x 64g, BK=64
__global__ __launch_bounds__(256, 2) void k_pool(float* __restrict__ ws) {
  __shared__ __align__(16) unsigned short sT[128*64];
  int ht = blockIdx.x, gt = blockIdx.y, b = blockIdx.z;
  int t = threadIdx.x, w = t >> 6, lane = t & 63;
  int wh = w >> 1, wg = w & 1, l15 = lane & 15, lk = lane >> 4;
  const unsigned short* t16 = (const unsigned short*)(ws + WS_T16);
  const unsigned short* bmp = (const unsigned short*)(ws + WS_BM);
  unsigned short* p16 = (unsigned short*)(ws + WS_P16);
  int h0 = ht*128, g0 = gt*128;
  f32x4 acc[4][4] = {};
  const unsigned short* brow[4];
#pragma unroll
  for (int fn = 0; fn < 4; ++fn) {
    int g = g0 + wg*64 + fn*16 + l15; if (g > Gg-1) g = Gg-1;
    brow[fn] = bmp + ((size_t)(b*GP + g)) * 64;
  }
  int bitoff = (lk & 1) * 8;
  int srow = t >> 1, sc0 = (t & 1) * 4;
  size_t sbase = ((size_t)(b*Hh + h0 + srow)) * NP;
  for (int st = 0; st < 16; ++st) {
    int k0 = st * 64;
#pragma unroll
    for (int i = 0; i < 4; ++i) {
      int cc = sc0 + i;
      *(short8*)&sT[SW(srow, cc)] = *(const short8*)(t16 + sbase + k0 + cc*8);
    }
    __syncthreads();
#pragma unroll
    for (int kk = 0; kk < 64; kk += 32) {
      f16x8 ah[4], bmf[4];
#pragma unroll
      for (int fm = 0; fm < 4; ++fm)
        ah[fm] = *(const f16x8*)&sT[SW(wh*64 + fm*16 + l15, (kk>>3) + lk)];
#pragma unroll
      for (int fn = 0; fn < 4; ++fn) {
        unsigned c = brow[fn][((k0 + kk) >> 4) + (lk >> 1)];
        short8 bs;
#pragma unroll
        for (int i = 0; i < 8; ++i)
          bs[i] = ((c >> (bitoff + i)) & 1) ? (short)0x3C00 : (short)0;
        bmf[fn] = *(const f16x8*)&bs;
      }
#pragma unroll
      for (int fm = 0; fm < 4; ++fm)
#pragma unroll
        for (int fn = 0; fn < 4; ++fn)
          acc[fm][fn] = MFMAH(ah[fm], bmf[fn], acc[fm][fn]);
    }
    __syncthreads();
  }
#pragma unroll
  for (int fm = 0; fm < 4; ++fm)
#pragma unroll
    for (int fn = 0; fn < 4; ++fn) {
      int h = h0 + wh*64 + fm*16 + lk*4;
      int g = g0 + wg*64 + fn*16 + l15;
      u16x4 v4;
#pragma unroll
      for (int j = 0; j < 4; ++j) v4[j] = f16b(acc[fm][fn][j] * (1.0f/Nn));
      *(u16x4*)(p16 + ((size_t)(b*GP + g)) * Hh + h) = v4;
    }
}

// ---------------- finalq GEMM (+inline q_graph): fq = Wcat@[pooled|lastE]^T + qg
// grid(ot=2, gt=4, b=64), block(256)=2x2 waves, wave tile 64o x 64g, K=512, BK=64
__global__ __launch_bounds__(256, 2) void k_finalq(const int* __restrict__ last_node,
                                                   const float* __restrict__ Wg,
                                                   float* __restrict__ ws) {
  __shared__ __align__(16) unsigned short sA[128*64], sB[128*64];
  __shared__ int lL[128];
  __shared__ float mean[256];
  __shared__ float qv[128];
  int ot = blockIdx.x, gt = blockIdx.y, b = blockIdx.z;
  int t = threadIdx.x, w = t >> 6, lane = t & 63;
  int wo = w >> 1, wg = w & 1, l15 = lane & 15, lk = lane >> 4;
  const unsigned short* wc = (const unsigned short*)(ws + WS_WC16);
  const unsigned short* p16 = (const unsigned short*)(ws + WS_P16);
  const unsigned short* e16 = (const unsigned short*)(ws + WS_E16);
  unsigned short* f16 = (unsigned short*)(ws + WS_F16);
  int o0 = ot*128, g0 = gt*128;
  if (t < 128) lL[t] = last_node[b*Gg + ((g0 + t) < Gg ? (g0 + t) : Gg-1)];
  {
    const float4* mp4 = (const float4*)(ws + WS_MP + (((size_t)(b * Hh + t)) << 4));
    float s = 0.f;
#pragma unroll
    for (int q = 0; q < 4; ++q) {
      float4 v = mp4[q];
      s += v.x + v.y + v.z + v.w;
    }
    mean[t] = s * (1.0f/Nn);
  }
  __syncthreads();
  if (t < 128) {
    const float4* wrow = (const float4*)(Wg + (size_t)(o0 + t) * Hh);
    float a = 0.f;
#pragma unroll
    for (int h4 = 0; h4 < 64; ++h4) {
      float4 wv = wrow[h4];
      a += mean[h4*4]*wv.x + mean[h4*4+1]*wv.y + mean[h4*4+2]*wv.z + mean[h4*4+3]*wv.w;
    }
    qv[t] = a;
  }
  __syncthreads();
  f32x4 acc[4][4] = {};
  int srow = t >> 1, sc0 = (t & 1) * 4;
  size_t abase = ((size_t)(o0 + srow)) * 512;
  size_t pbase = ((size_t)(b*GP + g0 + srow)) * Hh;
  size_t lbase = ((size_t)(b*Nn + lL[srow])) * Hh;
  for (int st = 0; st < 8; ++st) {
    int k0 = st * 64;
#pragma unroll
    for (int i = 0; i < 4; ++i) {
      int cc = sc0 + i;
      int d = SW(srow, cc);
      *(short8*)&sA[d] = *(const short8*)(wc + abase + k0 + cc*8);
      if (k0 < 256)
        *(short8*)&sB[d] = *(const short8*)(p16 + pbase + k0 + cc*8);
      else
        *(short8*)&sB[d] = *(const short8*)(e16 + lbase + (k0 - 256) + cc*8);
    }
    __syncthreads();
#pragma unroll
    for (int kk = 0; kk < 64; kk += 32) {
      f16x8 a[4], bb[4];
#pragma unroll
      for (int fm = 0; fm < 4; ++fm)
        a[fm] = *(const f16x8*)&sA[SW(wo*64 + fm*16 + l15, (kk>>3) + lk)];
#pragma unroll
      for (int fn = 0; fn < 4; ++fn)
        bb[fn] = *(const f16x8*)&sB[SW(wg*64 + fn*16 + l15, (kk>>3) + lk)];
#pragma unroll
      for (int fm = 0; fm < 4; ++fm)
#pragma unroll
        for (int fn = 0; fn < 4; ++fn)
          acc[fm][fn] = MFMAH(a[fm], bb[fn], acc[fm][fn]);
    }
    __syncthreads();
  }
#pragma unroll
  for (int fm = 0; fm < 4; ++fm) {
    int ob = wo*64 + fm*16 + lk*4;
    float q4[4] = { qv[ob+0], qv[ob+1], qv[ob+2], qv[ob+3] };
#pragma unroll
    for (int fn = 0; fn < 4; ++fn) {
      int g = g0 + wg*64 + fn*16 + l15;
      u16x4 v4;
#pragma unroll
      for (int j = 0; j < 4; ++j) v4[j] = f16b(acc[fm][fn][j] + q4[j]);
      *(u16x4*)(f16 + ((size_t)(b*GP + g)) * Hh + o0 + ob) = v4;
    }
  }
}

// ---------------- fused score + softmax + normalize ----------------
// 1D grid 1024, block 256 = 4 waves. Block owns 32 g x all n; p in registers.
// Decode groups 8 b's per XCD so per-XCD e-slices (4 MB) fill L2.
__global__ __launch_bounds__(256, 2) void k_score(const float* __restrict__ dists,
                                                  const int* __restrict__ last_node,
                                                  float* __restrict__ ws,
                                                  float* __restrict__ out) {
  __shared__ __align__(16) unsigned short sE[256*64], sF[32*64];
  __shared__ int lL[32];
  __shared__ float rsp[4][32];
  __shared__ float sInv[32];
  int id = blockIdx.x;
  int xcd = id & 7, seq = id >> 3;
  int b = xcd * 8 + (seq >> 4);
  int gt = seq & 15;
  int g0 = gt * 32;
  int t = threadIdx.x, w = t >> 6, lane = t & 63;
  int l15 = lane & 15, lk = lane >> 4;
  const unsigned short* e16 = (const unsigned short*)(ws + WS_E16);
  const unsigned short* f16 = (const unsigned short*)(ws + WS_F16);
  const unsigned short* bmp = (const unsigned short*)(ws + WS_BM);
  if (t < 32) lL[t] = last_node[b*Gg + ((g0 + t) < Gg ? (g0 + t) : Gg-1)];
  const float c2 = 0.70710678118654752f;
  float rsum[2] = {0.f, 0.f};
  unsigned pst[4][4][2][2];
#pragma unroll
  for (int pass = 0; pass < 4; ++pass) {
    f32x4 acc[4][2] = {};
    for (int st = 0; st < 4; ++st) {
      int k0 = st * 64;
      __syncthreads();
#pragma unroll
      for (int i = 0; i < 8; ++i) {
        int c = i * 256 + t;
        int row = c >> 3, ch = c & 7;
        int n = pass*256 + row; if (n > Nn-1) n = Nn-1;
        *(short8*)&sE[SW(row, ch)] =
            *(const short8*)(e16 + ((size_t)(b*Nn + n))*Hh + k0 + ch*8);
      }
      {
        int row = t >> 3, ch = t & 7;   // 32 rows x 8 chunks = 256
        *(short8*)&sF[SW(row, ch)] =
            *(const short8*)(f16 + ((size_t)(b*GP + g0 + row))*Hh + k0 + ch*8);
      }
      __syncthreads();
#pragma unroll
      for (int kk = 0; kk < 64; kk += 32) {
        f16x8 a[4], bb[2];
#pragma unroll
        for (int fm = 0; fm < 4; ++fm)
          a[fm] = *(const f16x8*)&sE[SW(w*64 + fm*16 + l15, (kk>>3) + lk)];
#pragma unroll
        for (int fn = 0; fn < 2; ++fn)
          bb[fn] = *(const f16x8*)&sF[SW(fn*16 + l15, (kk>>3) + lk)];
#pragma unroll
        for (int fm = 0; fm < 4; ++fm)
#pragma unroll
          for (int fn = 0; fn < 2; ++fn)
            acc[fm][fn] = MFMAH(a[fm], bb[fn], acc[fm][fn]);
      }
    }
    // per-pass epilogue: p = exp(10*tanh(s)-10), stash fp16 pairs, rsum
#pragma unroll
    for (int fm = 0; fm < 4; ++fm) {
      int n = pass*256 + w*64 + fm*16 + lk*4;
      if (n < Nn) {
#pragma unroll
        for (int fn = 0; fn < 2; ++fn) {
          int gl = fn*16 + l15, g = g0 + gl;
          if (g < Gg) {
            int L = lL[gl];
            float4 d4 = *(const float4*)(dists + ((size_t)(b*Nn + L))*Nn + n);
            unsigned cb = bmp[((size_t)(b*GP + g))*64 + (n >> 4)];
            int bo = n & 15;
            float dd[4] = {d4.x, d4.y, d4.z, d4.w};
            unsigned short h4[4];
#pragma unroll
            for (int j = 0; j < 4; ++j) {
              float s = fmaf(acc[fm][fn][j], 0.0625f, -dd[j] * c2);
              float e = __expf(-2.0f * fabsf(s));
              float r = __builtin_amdgcn_rcpf(1.0f + e);
              float m = fmaf(-20.0f, e * r, 10.0f);
              float parg = copysignf(m, s) - 10.0f;
              float p = ((cb >> (bo + j)) & 1) ? 0.f : __expf(parg);
              rsum[fn] += p;
              h4[j] = f16b(p);
            }
            pst[pass][fm][fn][0] = (unsigned)h4[0] | ((unsigned)h4[1] << 16);
            pst[pass][fm][fn][1] = (unsigned)h4[2] | ((unsigned)h4[3] << 16);
          }
        }
      }
    }
  }
  // block-wide row sums -> inverse
#pragma unroll
  for (int fn = 0; fn < 2; ++fn) {
    rsum[fn] += __shfl_xor(rsum[fn], 16);
    rsum[fn] += __shfl_xor(rsum[fn], 32);
  }
  if (lk == 0) { rsp[w][l15] = rsum[0]; rsp[w][16 + l15] = rsum[1]; }
  __syncthreads();
  if (t < 32) {
    float s = rsp[0][t] + rsp[1][t] + rsp[2][t] + rsp[3][t];
    sInv[t] = 1.0f / s;
  }
  __syncthreads();
  // normalize + write fp32 out
#pragma unroll
  for (int pass = 0; pass < 4; ++pass)
#pragma unroll
    for (int fm = 0; fm < 4; ++fm) {
      int n = pass*256 + w*64 + fm*16 + lk*4;
      if (n < Nn) {
#pragma unroll
        for (int fn = 0; fn < 2; ++fn) {
          int gl = fn*16 + l15, g = g0 + gl;
          if (g < Gg) {
            float iv = sInv[gl];
            unsigned u0 = pst[pass][fm][fn][0], u1 = pst[pass][fm][fn][1];
            float4 o4;
            o4.x = h2f((unsigned short)(u0 & 0xFFFF)) * iv;
            o4.y = h2f((unsigned short)(u0 >> 16)) * iv;
            o4.z = h2f((unsigned short)(u1 & 0xFFFF)) * iv;
            o4.w = h2f((unsigned short)(u1 >> 16)) * iv;
            *(float4*)(out + ((size_t)(b*Gg + g))*Nn + n) = o4;
          }
        }
      }
    }
}

extern "C" void kernel_launch(void* const* d_in, const int* in_sizes, int n_in,
                              void* d_out, int out_size, void* d_ws, size_t ws_size,
                              hipStream_t stream) {
  const float* emb       = (const float*)d_in[0];
  const float* dists     = (const float*)d_in[1];
  const int*   last_node = (const int*)d_in[2];
  const float* gm        = (const float*)d_in[3];
  const float* Wg        = (const float*)d_in[4];
  const float* Wf        = (const float*)d_in[5];
  const float* Wl        = (const float*)d_in[6];
  const float* Wv        = (const float*)d_in[7];
  float* out = (float*)d_out;
  float* ws  = (float*)d_ws;

  hipLaunchKernelGGL(k_front,  dim3(12544),     dim3(256), 0, stream, emb, gm, Wf, Wl, Wv, ws);
  hipLaunchKernelGGL(k_pool,   dim3(2,4,Bb),    dim3(256), 0, stream, ws);
  hipLaunchKernelGGL(k_finalq, dim3(2,4,Bb),    dim3(256), 0, stream, last_node, Wg, ws);
  hipLaunchKernelGGL(k_score,  dim3(1024),      dim3(256), 0, stream, dists, last_node, ws, out);
}

// Round 14
// 300.273 us; speedup vs baseline: 1.0410x; 1.0410x over previous
//
#include <hip/hip_runtime.h>
#include <hip/hip_fp16.h>
#include <math.h>

#define Bb 64
#define Nn 1000
#define Gg 500
#define Hh 256
#define GP 512
#define NP 1024

// float offsets into d_ws (total 30,375,936 floats = 121.5 MB)
#define WS_MP   0u           // [B][H][16] fp32 column-sum partials
#define WS_RS   262144u      // [B][GP] fp32 row sums (zeroed in k_front)
#define WS_BM   294912u      // u16 [B][GP][64] visited bitmask
#define WS_WC16 1343488u     // u16 [256][512] Wcat fp16
#define WS_E16  1409024u     // u16 [B][N][H] emb fp16 row-major
#define WS_T16  9601024u     // u16 [B][H][NP] embT fp16 (dead after k_pool)
#define WS_P16  17989632u    // u16 [B][GP][H] pooled fp16 (dead after k_finalq)
#define WS_F16  WS_T16       // u16 [B][GP][H] fq fp16 (overlays T16)
#define WS_PO   22183936u    // u16 [B][500][1024] unnorm p fp16

typedef __attribute__((ext_vector_type(8))) short short8;
typedef __attribute__((ext_vector_type(8))) _Float16 f16x8;
typedef __attribute__((ext_vector_type(4))) float f32x4;
typedef __attribute__((ext_vector_type(4))) unsigned short u16x4;

#define MFMAH(a,b,c) __builtin_amdgcn_mfma_f32_16x16x32_f16(a,b,c,0,0,0)
// swizzled LDS offset (shorts): 64-short rows, 8 chunks of 8 halves (16B)
#define SW(row, chunk) (((row) << 6) + ((((chunk) ^ ((row) & 7))) << 3))

__device__ __forceinline__ unsigned short f16b(float v) {
  return __half_as_ushort(__float2half(v));
}
__device__ __forceinline__ float h2f(unsigned short u) {
  return __half2float(__ushort_as_half(u));
}

// ---- front: prep (bid<4096) + bm (4096..12287) + wcat (..12543) + zero RS ----
__global__ __launch_bounds__(256) void k_front(const float* __restrict__ emb,
                                               const float* __restrict__ gm,
                                               const float* __restrict__ Wf,
                                               const float* __restrict__ Wl,
                                               const float* __restrict__ Wv,
                                               float* __restrict__ ws) {
  __shared__ float tile[64][68];
  __shared__ float colsum[16][64];
  int bid = blockIdx.x, t = threadIdx.x;
  if (bid < 4096) {
    // ---- prep: emb -> e16 + t16 + column-sum partials ----
    int nt = bid & 15, ht = (bid >> 4) & 3, b = bid >> 6;
    int c4 = (t & 15) * 4, r0 = t >> 4;
    int n0 = nt * 64, h0 = ht * 64;
    unsigned short* e16 = (unsigned short*)(ws + WS_E16);
    unsigned short* t16 = (unsigned short*)(ws + WS_T16);
    float cs0 = 0.f, cs1 = 0.f, cs2 = 0.f, cs3 = 0.f;
#pragma unroll
    for (int rr = 0; rr < 4; ++rr) {
      int r = r0 + rr * 16;
      int n = n0 + r;
      float4 v = {0.f, 0.f, 0.f, 0.f};
      if (n < Nn) {
        size_t idx = ((size_t)(b * Nn + n)) * Hh + h0 + c4;
        v = *(const float4*)(emb + idx);
        u16x4 e4 = { f16b(v.x), f16b(v.y), f16b(v.z), f16b(v.w) };
        *(u16x4*)(e16 + idx) = e4;
      }
      *(float4*)&tile[r][c4] = v;
      cs0 += v.x; cs1 += v.y; cs2 += v.z; cs3 += v.w;
    }
    colsum[r0][c4 + 0] = cs0; colsum[r0][c4 + 1] = cs1;
    colsum[r0][c4 + 2] = cs2; colsum[r0][c4 + 3] = cs3;
    __syncthreads();
    {
      int h_l = t >> 2, nseg = t & 3;
      short8 h8a, h8b;
#pragma unroll
      for (int i = 0; i < 16; ++i) {
        float v = tile[nseg * 16 + i][h_l];
        unsigned short hv = f16b(v);
        if (i < 8) h8a[i] = (short)hv;
        else       h8b[i-8] = (short)hv;
      }
      size_t base = ((size_t)(b * Hh + h0 + h_l)) * NP + n0 + nseg * 16;
      *(short8*)(t16 + base) = h8a; *(short8*)(t16 + base + 8) = h8b;
    }
    if (t < 64) {
      float s = 0.f;
#pragma unroll
      for (int i = 0; i < 16; ++i) s += colsum[i][t];
      ws[WS_MP + (((size_t)(b * Hh + h0 + t)) << 4) + nt] = s;
    }
  } else if (bid < 12288) {
    // ---- bm: gm -> bitmask ----
    int w = t >> 6, l = t & 63;
    int row = (bid - 4096) * 4 + w;          // b*GP + g
    int b = row >> 9, g = row & 511;
    unsigned long long* dst = (unsigned long long*)((unsigned short*)(ws + WS_BM) + (size_t)row * 64);
    if (g < Gg) {
      const float* src = gm + ((size_t)b * Gg + g) * Nn;
#pragma unroll
      for (int i = 0; i < 16; ++i) {
        int n = i * 64 + l;
        bool bit = (n < Nn) ? (src[n] < -1e30f) : false;
        unsigned long long m = __ballot(bit);
        if (l == i) dst[i] = m;
      }
    } else {
      if (l < 16) dst[l] = 0ull;
    }
  } else if (bid < 12544) {
    // ---- wcat fp16 ----
    int o = bid - 12288, k = t;
    unsigned short* wc = (unsigned short*)(ws + WS_WC16);
    wc[o*512 + k]       = f16b(Wv[o*Hh + k]);
    wc[o*512 + 256 + k] = f16b(Wl[o*Hh + k] + Wf[o*Hh + k]);
  } else {
    ws[WS_RS + (bid - 12544) * 256 + t] = 0.f;
  }
}

// ---------------- pool GEMM: pooled[g][h] = (1/N) mask @ emb ----------------
// grid(ht=2, gt=4, b=64), block(256)=2x2 waves, wave tile 64h x 64g, BK=64
__global__ __launch_bounds__(256, 2) void k_pool(float* __restrict__ ws) {
  __shared__ __align__(16) unsigned short sT[128*64];
  int ht = blockIdx.x, gt = blockIdx.y, b = blockIdx.z;
  int t = threadIdx.x, w = t >> 6, lane = t & 63;
  int wh = w >> 1, wg = w & 1, l15 = lane & 15, lk = lane >> 4;
  const unsigned short* t16 = (const unsigned short*)(ws + WS_T16);
  const unsigned short* bmp = (const unsigned short*)(ws + WS_BM);
  unsigned short* p16 = (unsigned short*)(ws + WS_P16);
  int h0 = ht*128, g0 = gt*128;
  f32x4 acc[4][4] = {};
  const unsigned short* brow[4];
#pragma unroll
  for (int fn = 0; fn < 4; ++fn) {
    int g = g0 + wg*64 + fn*16 + l15; if (g > Gg-1) g = Gg-1;
    brow[fn] = bmp + ((size_t)(b*GP + g)) * 64;
  }
  int bitoff = (lk & 1) * 8;
  int srow = t >> 1, sc0 = (t & 1) * 4;
  size_t sbase = ((size_t)(b*Hh + h0 + srow)) * NP;
  for (int st = 0; st < 16; ++st) {
    int k0 = st * 64;
#pragma unroll
    for (int i = 0; i < 4; ++i) {
      int cc = sc0 + i;
      *(short8*)&sT[SW(srow, cc)] = *(const short8*)(t16 + sbase + k0 + cc*8);
    }
    __syncthreads();
#pragma unroll
    for (int kk = 0; kk < 64; kk += 32) {
      f16x8 ah[4], bmf[4];
#pragma unroll
      for (int fm = 0; fm < 4; ++fm)
        ah[fm] = *(const f16x8*)&sT[SW(wh*64 + fm*16 + l15, (kk>>3) + lk)];
#pragma unroll
      for (int fn = 0; fn < 4; ++fn) {
        unsigned c = brow[fn][((k0 + kk) >> 4) + (lk >> 1)];
        short8 bs;
#pragma unroll
        for (int i = 0; i < 8; ++i)
          bs[i] = ((c >> (bitoff + i)) & 1) ? (short)0x3C00 : (short)0;
        bmf[fn] = *(const f16x8*)&bs;
      }
#pragma unroll
      for (int fm = 0; fm < 4; ++fm)
#pragma unroll
        for (int fn = 0; fn < 4; ++fn)
          acc[fm][fn] = MFMAH(ah[fm], bmf[fn], acc[fm][fn]);
    }
    __syncthreads();
  }
#pragma unroll
  for (int fm = 0; fm < 4; ++fm)
#pragma unroll
    for (int fn = 0; fn < 4; ++fn) {
      int h = h0 + wh*64 + fm*16 + lk*4;
      int g = g0 + wg*64 + fn*16 + l15;
      u16x4 v4;
#pragma unroll
      for (int j = 0; j < 4; ++j) v4[j] = f16b(acc[fm][fn][j] * (1.0f/Nn));
      *(u16x4*)(p16 + ((size_t)(b*GP + g)) * Hh + h) = v4;
    }
}

// ---------------- finalq GEMM (+inline q_graph): fq = Wcat@[pooled|lastE]^T + qg
// grid(ot=2, gt=4, b=64), block(256)=2x2 waves, wave tile 64o x 64g, K=512, BK=64
__global__ __launch_bounds__(256, 2) void k_finalq(const int* __restrict__ last_node,
                                                   const float* __restrict__ Wg,
                                                   float* __restrict__ ws) {
  __shared__ __align__(16) unsigned short sA[128*64], sB[128*64];
  __shared__ int lL[128];
  __shared__ float mean[256];
  __shared__ float qv[128];
  int ot = blockIdx.x, gt = blockIdx.y, b = blockIdx.z;
  int t = threadIdx.x, w = t >> 6, lane = t & 63;
  int wo = w >> 1, wg = w & 1, l15 = lane & 15, lk = lane >> 4;
  const unsigned short* wc = (const unsigned short*)(ws + WS_WC16);
  const unsigned short* p16 = (const unsigned short*)(ws + WS_P16);
  const unsigned short* e16 = (const unsigned short*)(ws + WS_E16);
  unsigned short* f16 = (unsigned short*)(ws + WS_F16);
  int o0 = ot*128, g0 = gt*128;
  if (t < 128) lL[t] = last_node[b*Gg + ((g0 + t) < Gg ? (g0 + t) : Gg-1)];
  {
    const float4* mp4 = (const float4*)(ws + WS_MP + (((size_t)(b * Hh + t)) << 4));
    float s = 0.f;
#pragma unroll
    for (int q = 0; q < 4; ++q) {
      float4 v = mp4[q];
      s += v.x + v.y + v.z + v.w;
    }
    mean[t] = s * (1.0f/Nn);
  }
  __syncthreads();
  if (t < 128) {
    const float4* wrow = (const float4*)(Wg + (size_t)(o0 + t) * Hh);
    float a = 0.f;
#pragma unroll
    for (int h4 = 0; h4 < 64; ++h4) {
      float4 wv = wrow[h4];
      a += mean[h4*4]*wv.x + mean[h4*4+1]*wv.y + mean[h4*4+2]*wv.z + mean[h4*4+3]*wv.w;
    }
    qv[t] = a;
  }
  __syncthreads();
  f32x4 acc[4][4] = {};
  int srow = t >> 1, sc0 = (t & 1) * 4;
  size_t abase = ((size_t)(o0 + srow)) * 512;
  size_t pbase = ((size_t)(b*GP + g0 + srow)) * Hh;
  size_t lbase = ((size_t)(b*Nn + lL[srow])) * Hh;
  for (int st = 0; st < 8; ++st) {
    int k0 = st * 64;
#pragma unroll
    for (int i = 0; i < 4; ++i) {
      int cc = sc0 + i;
      int d = SW(srow, cc);
      *(short8*)&sA[d] = *(const short8*)(wc + abase + k0 + cc*8);
      if (k0 < 256)
        *(short8*)&sB[d] = *(const short8*)(p16 + pbase + k0 + cc*8);
      else
        *(short8*)&sB[d] = *(const short8*)(e16 + lbase + (k0 - 256) + cc*8);
    }
    __syncthreads();
#pragma unroll
    for (int kk = 0; kk < 64; kk += 32) {
      f16x8 a[4], bb[4];
#pragma unroll
      for (int fm = 0; fm < 4; ++fm)
        a[fm] = *(const f16x8*)&sA[SW(wo*64 + fm*16 + l15, (kk>>3) + lk)];
#pragma unroll
      for (int fn = 0; fn < 4; ++fn)
        bb[fn] = *(const f16x8*)&sB[SW(wg*64 + fn*16 + l15, (kk>>3) + lk)];
#pragma unroll
      for (int fm = 0; fm < 4; ++fm)
#pragma unroll
        for (int fn = 0; fn < 4; ++fn)
          acc[fm][fn] = MFMAH(a[fm], bb[fn], acc[fm][fn]);
    }
    __syncthreads();
  }
#pragma unroll
  for (int fm = 0; fm < 4; ++fm) {
    int ob = wo*64 + fm*16 + lk*4;
    float q4[4] = { qv[ob+0], qv[ob+1], qv[ob+2], qv[ob+3] };
#pragma unroll
    for (int fn = 0; fn < 4; ++fn) {
      int g = g0 + wg*64 + fn*16 + l15;
      u16x4 v4;
#pragma unroll
      for (int j = 0; j < 4; ++j) v4[j] = f16b(acc[fm][fn][j] + q4[j]);
      *(u16x4*)(f16 + ((size_t)(b*GP + g)) * Hh + o0 + ob) = v4;
    }
  }
}

// ---------------- score GEMM + fp16 p + rowsum atomics ----------------
// 1D grid 2048, XCD-swizzled decode -> (gt,nt,b); block(256)=2x2 waves,
// wave tile 64n x 64g, K=256, BK=64. Same-XCD neighbors share the e-tile.
__global__ __launch_bounds__(256, 4) void k_score(const float* __restrict__ dists,
                                                  const int* __restrict__ last_node,
                                                  float* __restrict__ ws) {
  __shared__ __align__(16) unsigned short sE[128*64], sF[128*64];
  __shared__ int lL[128];
  int id = blockIdx.x;
  int swz = ((id & 7) << 8) | (id >> 3);   // bijective: 2048 = 8 * 256
  int gt = swz & 3, nt = (swz >> 2) & 7, b = swz >> 5;
  int t = threadIdx.x, w = t >> 6, lane = t & 63;
  int wn = w >> 1, wg = w & 1, l15 = lane & 15, lk = lane >> 4;
  const unsigned short* e16 = (const unsigned short*)(ws + WS_E16);
  const unsigned short* f16 = (const unsigned short*)(ws + WS_F16);
  const unsigned short* bmp = (const unsigned short*)(ws + WS_BM);
  unsigned short* po = (unsigned short*)(ws + WS_PO);
  float* rs = ws + WS_RS;
  int n0 = nt*128, g0 = gt*128;
  if (t < 128) lL[t] = last_node[b*Gg + ((g0 + t) < Gg ? (g0 + t) : Gg-1)];
  __syncthreads();
  f32x4 acc[4][4] = {};
  int srow = t >> 1, sc0 = (t & 1) * 4;
  int nr = n0 + srow; if (nr > Nn-1) nr = Nn-1;
  size_t ebase = ((size_t)(b*Nn + nr)) * Hh;
  size_t fbase = ((size_t)(b*GP + g0 + srow)) * Hh;
  for (int st = 0; st < 4; ++st) {
    int k0 = st * 64;
#pragma unroll
    for (int i = 0; i < 4; ++i) {
      int cc = sc0 + i;
      int d = SW(srow, cc);
      *(short8*)&sE[d] = *(const short8*)(e16 + ebase + k0 + cc*8);
      *(short8*)&sF[d] = *(const short8*)(f16 + fbase + k0 + cc*8);
    }
    __syncthreads();
#pragma unroll
    for (int kk = 0; kk < 64; kk += 32) {
      f16x8 a[4], bb[4];
#pragma unroll
      for (int fm = 0; fm < 4; ++fm)
        a[fm] = *(const f16x8*)&sE[SW(wn*64 + fm*16 + l15, (kk>>3) + lk)];
#pragma unroll
      for (int fn = 0; fn < 4; ++fn)
        bb[fn] = *(const f16x8*)&sF[SW(wg*64 + fn*16 + l15, (kk>>3) + lk)];
#pragma unroll
      for (int fm = 0; fm < 4; ++fm)
#pragma unroll
        for (int fn = 0; fn < 4; ++fn)
          acc[fm][fn] = MFMAH(a[fm], bb[fn], acc[fm][fn]);
    }
    __syncthreads();
  }
  const float c2 = 0.70710678118654752f;
  float rsum[4] = {0.f, 0.f, 0.f, 0.f};
#pragma unroll
  for (int fn = 0; fn < 4; ++fn) {
    int gl = wg*64 + fn*16 + l15;
    int g = g0 + gl;
    if (g < Gg) {
      int L = lL[gl];
      const float* drow = dists + ((size_t)(b*Nn + L)) * Nn;
      const unsigned short* bmr = bmp + ((size_t)(b*GP + g)) * 64;
      unsigned short* prow = po + ((size_t)(b*Gg + g)) * 1024;
#pragma unroll
      for (int fm = 0; fm < 4; ++fm) {
        int n = n0 + wn*64 + fm*16 + lk*4;
        if (n < Nn) {
          float4 d4 = *(const float4*)(drow + n);
          unsigned cb = bmr[n >> 4];
          int bo = n & 15;
          float dd[4] = {d4.x, d4.y, d4.z, d4.w};
          unsigned short h4[4];
#pragma unroll
          for (int j = 0; j < 4; ++j) {
            // p = exp(10*tanh(s) - 10), exp2-domain, rcp-approx division
            float s = fmaf(acc[fm][fn][j], 0.0625f, -dd[j] * c2);
            float e = __expf(-2.0f * fabsf(s));
            float r = __builtin_amdgcn_rcpf(1.0f + e);
            float m = fmaf(-20.0f, e * r, 10.0f);   // = 10*tanh(|s|)
            float parg = copysignf(m, s) - 10.0f;
            float p = ((cb >> (bo + j)) & 1) ? 0.f : __expf(parg);
            rsum[fn] += p;
            h4[j] = f16b(p);
          }
          uint2 u = { (unsigned)h4[0] | ((unsigned)h4[1] << 16),
                      (unsigned)h4[2] | ((unsigned)h4[3] << 16) };
          *(uint2*)(prow + n) = u;
        }
      }
    }
  }
#pragma unroll
  for (int fn = 0; fn < 4; ++fn) {
    rsum[fn] += __shfl_xor(rsum[fn], 16);
    rsum[fn] += __shfl_xor(rsum[fn], 32);
    int g = g0 + wg*64 + fn*16 + l15;
    if (lk == 0 && g < Gg) atomicAdd(rs + b*GP + g, rsum[fn]);
  }
}

// ---------------- normalize (wide): out[g][n] = fp16 p * (1/rs): grid(15625) --
__global__ __launch_bounds__(256) void k_norm(const float* __restrict__ ws,
                                              float* __restrict__ out) {
  int idx = blockIdx.x * 256 + threadIdx.x;   // 8-elem index, total 4,000,000
  int bg = idx / 125;                         // b*Gg + g
  int n = (idx - bg * 125) * 8;
  int b = bg / Gg, g = bg - b * Gg;
  const unsigned short* po = (const unsigned short*)(ws + WS_PO);
  float inv = 1.0f / ws[WS_RS + b*GP + g];
  uint4 u = *(const uint4*)(po + (size_t)bg * 1024 + n);
  float* orow = out + (size_t)bg * Nn + n;
  float4 o0, o1;
  o0.x = h2f((unsigned short)(u.x & 0xFFFF)) * inv;
  o0.y = h2f((unsigned short)(u.x >> 16)) * inv;
  o0.z = h2f((unsigned short)(u.y & 0xFFFF)) * inv;
  o0.w = h2f((unsigned short)(u.y >> 16)) * inv;
  o1.x = h2f((unsigned short)(u.z & 0xFFFF)) * inv;
  o1.y = h2f((unsigned short)(u.z >> 16)) * inv;
  o1.z = h2f((unsigned short)(u.w & 0xFFFF)) * inv;
  o1.w = h2f((unsigned short)(u.w >> 16)) * inv;
  *(float4*)orow = o0;
  *(float4*)(orow + 4) = o1;
}

extern "C" void kernel_launch(void* const* d_in, const int* in_sizes, int n_in,
                              void* d_out, int out_size, void* d_ws, size_t ws_size,
                              hipStream_t stream) {
  const float* emb       = (const float*)d_in[0];
  const float* dists     = (const float*)d_in[1];
  const int*   last_node = (const int*)d_in[2];
  const float* gm        = (const float*)d_in[3];
  const float* Wg        = (const float*)d_in[4];
  const float* Wf        = (const float*)d_in[5];
  const float* Wl        = (const float*)d_in[6];
  const float* Wv        = (const float*)d_in[7];
  float* out = (float*)d_out;
  float* ws  = (float*)d_ws;

  hipLaunchKernelGGL(k_front,  dim3(12672),     dim3(256), 0, stream, emb, gm, Wf, Wl, Wv, ws);
  hipLaunchKernelGGL(k_pool,   dim3(2,4,Bb),    dim3(256), 0, stream, ws);
  hipLaunchKernelGGL(k_finalq, dim3(2,4,Bb),    dim3(256), 0, stream, last_node, Wg, ws);
  hipLaunchKernelGGL(k_score,  dim3(2048),      dim3(256), 0, stream, dists, last_node, ws);
  hipLaunchKernelGGL(k_norm,   dim3(15625),     dim3(256), 0, stream, ws, out);
}

// Round 15
// 300.061 us; speedup vs baseline: 1.0418x; 1.0007x over previous
//
#include <hip/hip_runtime.h>
#include <hip/hip_fp16.h>
#include <math.h>

#define Bb 64
#define Nn 1000
#define Gg 500
#define Hh 256
#define GP 512
#define NP 1024

// float offsets into d_ws (total 30,375,936 floats = 121.5 MB)
#define WS_MP   0u           // [B][H][16] fp32 column-sum partials
#define WS_RS   262144u      // [B][GP] fp32 row sums (zeroed in k_front)
#define WS_BM   294912u      // u16 [B][GP][64] visited bitmask
#define WS_WC16 1343488u     // u16 [256][512] Wcat fp16
#define WS_E16  1409024u     // u16 [B][N][H] emb fp16 row-major
#define WS_T16  9601024u     // u16 [B][H][NP] embT fp16 (dead after k_pool)
#define WS_P16  17989632u    // u16 [B][GP][H] pooled fp16 (dead after k_finalq)
#define WS_F16  WS_T16       // u16 [B][GP][H] fq fp16 (overlays T16)
#define WS_PO   22183936u    // u16 [B][500][1024] unnorm p fp16

typedef __attribute__((ext_vector_type(8))) short short8;
typedef __attribute__((ext_vector_type(8))) _Float16 f16x8;
typedef __attribute__((ext_vector_type(4))) float f32x4;
typedef __attribute__((ext_vector_type(4))) unsigned short u16x4;

#define MFMAH(a,b,c) __builtin_amdgcn_mfma_f32_16x16x32_f16(a,b,c,0,0,0)
// swizzled LDS offset (shorts): 64-short rows, 8 chunks of 8 halves (16B)
#define SW(row, chunk) (((row) << 6) + ((((chunk) ^ ((row) & 7))) << 3))

__device__ __forceinline__ unsigned short f16b(float v) {
  return __half_as_ushort(__float2half(v));
}
__device__ __forceinline__ float h2f(unsigned short u) {
  return __half2float(__ushort_as_half(u));
}

// ---- front: prep (bid<4096) + bm (4096..12287) + wcat (..12543) + zero RS ----
__global__ __launch_bounds__(256) void k_front(const float* __restrict__ emb,
                                               const float* __restrict__ gm,
                                               const float* __restrict__ Wf,
                                               const float* __restrict__ Wl,
                                               const float* __restrict__ Wv,
                                               float* __restrict__ ws) {
  __shared__ float tile[64][68];
  __shared__ float colsum[16][64];
  int bid = blockIdx.x, t = threadIdx.x;
  if (bid < 4096) {
    // ---- prep: emb -> e16 + t16 + column-sum partials ----
    int nt = bid & 15, ht = (bid >> 4) & 3, b = bid >> 6;
    int c4 = (t & 15) * 4, r0 = t >> 4;
    int n0 = nt * 64, h0 = ht * 64;
    unsigned short* e16 = (unsigned short*)(ws + WS_E16);
    unsigned short* t16 = (unsigned short*)(ws + WS_T16);
    float cs0 = 0.f, cs1 = 0.f, cs2 = 0.f, cs3 = 0.f;
#pragma unroll
    for (int rr = 0; rr < 4; ++rr) {
      int r = r0 + rr * 16;
      int n = n0 + r;
      float4 v = {0.f, 0.f, 0.f, 0.f};
      if (n < Nn) {
        size_t idx = ((size_t)(b * Nn + n)) * Hh + h0 + c4;
        v = *(const float4*)(emb + idx);
        u16x4 e4 = { f16b(v.x), f16b(v.y), f16b(v.z), f16b(v.w) };
        *(u16x4*)(e16 + idx) = e4;
      }
      *(float4*)&tile[r][c4] = v;
      cs0 += v.x; cs1 += v.y; cs2 += v.z; cs3 += v.w;
    }
    colsum[r0][c4 + 0] = cs0; colsum[r0][c4 + 1] = cs1;
    colsum[r0][c4 + 2] = cs2; colsum[r0][c4 + 3] = cs3;
    __syncthreads();
    {
      int h_l = t >> 2, nseg = t & 3;
      short8 h8a, h8b;
#pragma unroll
      for (int i = 0; i < 16; ++i) {
        float v = tile[nseg * 16 + i][h_l];
        unsigned short hv = f16b(v);
        if (i < 8) h8a[i] = (short)hv;
        else       h8b[i-8] = (short)hv;
      }
      size_t base = ((size_t)(b * Hh + h0 + h_l)) * NP + n0 + nseg * 16;
      *(short8*)(t16 + base) = h8a; *(short8*)(t16 + base + 8) = h8b;
    }
    if (t < 64) {
      float s = 0.f;
#pragma unroll
      for (int i = 0; i < 16; ++i) s += colsum[i][t];
      ws[WS_MP + (((size_t)(b * Hh + h0 + t)) << 4) + nt] = s;
    }
  } else if (bid < 12288) {
    // ---- bm: gm -> bitmask ----
    int w = t >> 6, l = t & 63;
    int row = (bid - 4096) * 4 + w;          // b*GP + g
    int b = row >> 9, g = row & 511;
    unsigned long long* dst = (unsigned long long*)((unsigned short*)(ws + WS_BM) + (size_t)row * 64);
    if (g < Gg) {
      const float* src = gm + ((size_t)b * Gg + g) * Nn;
#pragma unroll
      for (int i = 0; i < 16; ++i) {
        int n = i * 64 + l;
        bool bit = (n < Nn) ? (src[n] < -1e30f) : false;
        unsigned long long m = __ballot(bit);
        if (l == i) dst[i] = m;
      }
    } else {
      if (l < 16) dst[l] = 0ull;
    }
  } else if (bid < 12544) {
    // ---- wcat fp16 ----
    int o = bid - 12288, k = t;
    unsigned short* wc = (unsigned short*)(ws + WS_WC16);
    wc[o*512 + k]       = f16b(Wv[o*Hh + k]);
    wc[o*512 + 256 + k] = f16b(Wl[o*Hh + k] + Wf[o*Hh + k]);
  } else {
    ws[WS_RS + (bid - 12544) * 256 + t] = 0.f;
  }
}

// ---------------- pool GEMM: pooled[g][h] = (1/N) mask @ emb ----------------
// 1D grid 512, XCD-affine decode: all 8 blocks of one b on one XCD so the
// 512 KB t16 slice is fetched once per L2. block(256)=2x2 waves, 64h x 64g.
__global__ __launch_bounds__(256, 2) void k_pool(float* __restrict__ ws) {
  __shared__ __align__(16) unsigned short sT[128*64];
  int id = blockIdx.x;
  int xcd = id & 7, seq = id >> 3;                // 512 = 8 xcd * 64
  int b = xcd * 8 + (seq >> 3);
  int inner = seq & 7, ht = inner >> 2, gt = inner & 3;
  int t = threadIdx.x, w = t >> 6, lane = t & 63;
  int wh = w >> 1, wg = w & 1, l15 = lane & 15, lk = lane >> 4;
  const unsigned short* t16 = (const unsigned short*)(ws + WS_T16);
  const unsigned short* bmp = (const unsigned short*)(ws + WS_BM);
  unsigned short* p16 = (unsigned short*)(ws + WS_P16);
  int h0 = ht*128, g0 = gt*128;
  f32x4 acc[4][4] = {};
  const unsigned short* brow[4];
#pragma unroll
  for (int fn = 0; fn < 4; ++fn) {
    int g = g0 + wg*64 + fn*16 + l15; if (g > Gg-1) g = Gg-1;
    brow[fn] = bmp + ((size_t)(b*GP + g)) * 64;
  }
  int bitoff = (lk & 1) * 8;
  int srow = t >> 1, sc0 = (t & 1) * 4;
  size_t sbase = ((size_t)(b*Hh + h0 + srow)) * NP;
  for (int st = 0; st < 16; ++st) {
    int k0 = st * 64;
#pragma unroll
    for (int i = 0; i < 4; ++i) {
      int cc = sc0 + i;
      *(short8*)&sT[SW(srow, cc)] = *(const short8*)(t16 + sbase + k0 + cc*8);
    }
    __syncthreads();
#pragma unroll
    for (int kk = 0; kk < 64; kk += 32) {
      f16x8 ah[4], bmf[4];
#pragma unroll
      for (int fm = 0; fm < 4; ++fm)
        ah[fm] = *(const f16x8*)&sT[SW(wh*64 + fm*16 + l15, (kk>>3) + lk)];
#pragma unroll
      for (int fn = 0; fn < 4; ++fn) {
        unsigned c = brow[fn][((k0 + kk) >> 4) + (lk >> 1)];
        short8 bs;
#pragma unroll
        for (int i = 0; i < 8; ++i)
          bs[i] = ((c >> (bitoff + i)) & 1) ? (short)0x3C00 : (short)0;
        bmf[fn] = *(const f16x8*)&bs;
      }
#pragma unroll
      for (int fm = 0; fm < 4; ++fm)
#pragma unroll
        for (int fn = 0; fn < 4; ++fn)
          acc[fm][fn] = MFMAH(ah[fm], bmf[fn], acc[fm][fn]);
    }
    __syncthreads();
  }
#pragma unroll
  for (int fm = 0; fm < 4; ++fm)
#pragma unroll
    for (int fn = 0; fn < 4; ++fn) {
      int h = h0 + wh*64 + fm*16 + lk*4;
      int g = g0 + wg*64 + fn*16 + l15;
      u16x4 v4;
#pragma unroll
      for (int j = 0; j < 4; ++j) v4[j] = f16b(acc[fm][fn][j] * (1.0f/Nn));
      *(u16x4*)(p16 + ((size_t)(b*GP + g)) * Hh + h) = v4;
    }
}

// ---------------- finalq GEMM (+inline q_graph): fq = Wcat@[pooled|lastE]^T + qg
// 1D grid 512, XCD-affine decode; block(256)=2x2 waves, 64o x 64g, K=512
__global__ __launch_bounds__(256, 2) void k_finalq(const int* __restrict__ last_node,
                                                   const float* __restrict__ Wg,
                                                   float* __restrict__ ws) {
  __shared__ __align__(16) unsigned short sA[128*64], sB[128*64];
  __shared__ int lL[128];
  __shared__ float mean[256];
  __shared__ float qv[128];
  int id = blockIdx.x;
  int xcd = id & 7, seq = id >> 3;
  int b = xcd * 8 + (seq >> 3);
  int inner = seq & 7, ot = inner >> 2, gt = inner & 3;
  int t = threadIdx.x, w = t >> 6, lane = t & 63;
  int wo = w >> 1, wg = w & 1, l15 = lane & 15, lk = lane >> 4;
  const unsigned short* wc = (const unsigned short*)(ws + WS_WC16);
  const unsigned short* p16 = (const unsigned short*)(ws + WS_P16);
  const unsigned short* e16 = (const unsigned short*)(ws + WS_E16);
  unsigned short* f16 = (unsigned short*)(ws + WS_F16);
  int o0 = ot*128, g0 = gt*128;
  if (t < 128) lL[t] = last_node[b*Gg + ((g0 + t) < Gg ? (g0 + t) : Gg-1)];
  {
    const float4* mp4 = (const float4*)(ws + WS_MP + (((size_t)(b * Hh + t)) << 4));
    float s = 0.f;
#pragma unroll
    for (int q = 0; q < 4; ++q) {
      float4 v = mp4[q];
      s += v.x + v.y + v.z + v.w;
    }
    mean[t] = s * (1.0f/Nn);
  }
  __syncthreads();
  if (t < 128) {
    const float4* wrow = (const float4*)(Wg + (size_t)(o0 + t) * Hh);
    float a = 0.f;
#pragma unroll
    for (int h4 = 0; h4 < 64; ++h4) {
      float4 wv = wrow[h4];
      a += mean[h4*4]*wv.x + mean[h4*4+1]*wv.y + mean[h4*4+2]*wv.z + mean[h4*4+3]*wv.w;
    }
    qv[t] = a;
  }
  __syncthreads();
  f32x4 acc[4][4] = {};
  int srow = t >> 1, sc0 = (t & 1) * 4;
  size_t abase = ((size_t)(o0 + srow)) * 512;
  size_t pbase = ((size_t)(b*GP + g0 + srow)) * Hh;
  size_t lbase = ((size_t)(b*Nn + lL[srow])) * Hh;
  for (int st = 0; st < 8; ++st) {
    int k0 = st * 64;
#pragma unroll
    for (int i = 0; i < 4; ++i) {
      int cc = sc0 + i;
      int d = SW(srow, cc);
      *(short8*)&sA[d] = *(const short8*)(wc + abase + k0 + cc*8);
      if (k0 < 256)
        *(short8*)&sB[d] = *(const short8*)(p16 + pbase + k0 + cc*8);
      else
        *(short8*)&sB[d] = *(const short8*)(e16 + lbase + (k0 - 256) + cc*8);
    }
    __syncthreads();
#pragma unroll
    for (int kk = 0; kk < 64; kk += 32) {
      f16x8 a[4], bb[4];
#pragma unroll
      for (int fm = 0; fm < 4; ++fm)
        a[fm] = *(const f16x8*)&sA[SW(wo*64 + fm*16 + l15, (kk>>3) + lk)];
#pragma unroll
      for (int fn = 0; fn < 4; ++fn)
        bb[fn] = *(const f16x8*)&sB[SW(wg*64 + fn*16 + l15, (kk>>3) + lk)];
#pragma unroll
      for (int fm = 0; fm < 4; ++fm)
#pragma unroll
        for (int fn = 0; fn < 4; ++fn)
          acc[fm][fn] = MFMAH(a[fm], bb[fn], acc[fm][fn]);
    }
    __syncthreads();
  }
#pragma unroll
  for (int fm = 0; fm < 4; ++fm) {
    int ob = wo*64 + fm*16 + lk*4;
    float q4[4] = { qv[ob+0], qv[ob+1], qv[ob+2], qv[ob+3] };
#pragma unroll
    for (int fn = 0; fn < 4; ++fn) {
      int g = g0 + wg*64 + fn*16 + l15;
      u16x4 v4;
#pragma unroll
      for (int j = 0; j < 4; ++j) v4[j] = f16b(acc[fm][fn][j] + q4[j]);
      *(u16x4*)(f16 + ((size_t)(b*GP + g)) * Hh + o0 + ob) = v4;
    }
  }
}

// ---------------- score GEMM + fp16 p + rowsum atomics ----------------
// 1D grid 2048, XCD-swizzled decode -> (gt,nt,b); block(256)=2x2 waves,
// wave tile 64n x 64g, K=256, BK=64. Same-XCD neighbors share the e-tile.
__global__ __launch_bounds__(256, 4) void k_score(const float* __restrict__ dists,
                                                  const int* __restrict__ last_node,
                                                  float* __restrict__ ws) {
  __shared__ __align__(16) unsigned short sE[128*64], sF[128*64];
  __shared__ int lL[128];
  int id = blockIdx.x;
  int swz = ((id & 7) << 8) | (id >> 3);   // bijective: 2048 = 8 * 256
  int gt = swz & 3, nt = (swz >> 2) & 7, b = swz >> 5;
  int t = threadIdx.x, w = t >> 6, lane = t & 63;
  int wn = w >> 1, wg = w & 1, l15 = lane & 15, lk = lane >> 4;
  const unsigned short* e16 = (const unsigned short*)(ws + WS_E16);
  const unsigned short* f16 = (const unsigned short*)(ws + WS_F16);
  const unsigned short* bmp = (const unsigned short*)(ws + WS_BM);
  unsigned short* po = (unsigned short*)(ws + WS_PO);
  float* rs = ws + WS_RS;
  int n0 = nt*128, g0 = gt*128;
  if (t < 128) lL[t] = last_node[b*Gg + ((g0 + t) < Gg ? (g0 + t) : Gg-1)];
  __syncthreads();
  f32x4 acc[4][4] = {};
  int srow = t >> 1, sc0 = (t & 1) * 4;
  int nr = n0 + srow; if (nr > Nn-1) nr = Nn-1;
  size_t ebase = ((size_t)(b*Nn + nr)) * Hh;
  size_t fbase = ((size_t)(b*GP + g0 + srow)) * Hh;
  for (int st = 0; st < 4; ++st) {
    int k0 = st * 64;
#pragma unroll
    for (int i = 0; i < 4; ++i) {
      int cc = sc0 + i;
      int d = SW(srow, cc);
      *(short8*)&sE[d] = *(const short8*)(e16 + ebase + k0 + cc*8);
      *(short8*)&sF[d] = *(const short8*)(f16 + fbase + k0 + cc*8);
    }
    __syncthreads();
#pragma unroll
    for (int kk = 0; kk < 64; kk += 32) {
      f16x8 a[4], bb[4];
#pragma unroll
      for (int fm = 0; fm < 4; ++fm)
        a[fm] = *(const f16x8*)&sE[SW(wn*64 + fm*16 + l15, (kk>>3) + lk)];
#pragma unroll
      for (int fn = 0; fn < 4; ++fn)
        bb[fn] = *(const f16x8*)&sF[SW(wg*64 + fn*16 + l15, (kk>>3) + lk)];
#pragma unroll
      for (int fm = 0; fm < 4; ++fm)
#pragma unroll
        for (int fn = 0; fn < 4; ++fn)
          acc[fm][fn] = MFMAH(a[fm], bb[fn], acc[fm][fn]);
    }
    __syncthreads();
  }
  const float c2 = 0.70710678118654752f;
  float rsum[4] = {0.f, 0.f, 0.f, 0.f};
#pragma unroll
  for (int fn = 0; fn < 4; ++fn) {
    int gl = wg*64 + fn*16 + l15;
    int g = g0 + gl;
    if (g < Gg) {
      int L = lL[gl];
      const float* drow = dists + ((size_t)(b*Nn + L)) * Nn;
      const unsigned short* bmr = bmp + ((size_t)(b*GP + g)) * 64;
      unsigned short* prow = po + ((size_t)(b*Gg + g)) * 1024;
#pragma unroll
      for (int fm = 0; fm < 4; ++fm) {
        int n = n0 + wn*64 + fm*16 + lk*4;
        if (n < Nn) {
          float4 d4 = *(const float4*)(drow + n);
          unsigned cb = bmr[n >> 4];
          int bo = n & 15;
          float dd[4] = {d4.x, d4.y, d4.z, d4.w};
          unsigned short h4[4];
#pragma unroll
          for (int j = 0; j < 4; ++j) {
            // p = exp(10*tanh(s) - 10), exp2-domain, rcp-approx division
            float s = fmaf(acc[fm][fn][j], 0.0625f, -dd[j] * c2);
            float e = __expf(-2.0f * fabsf(s));
            float r = __builtin_amdgcn_rcpf(1.0f + e);
            float m = fmaf(-20.0f, e * r, 10.0f);   // = 10*tanh(|s|)
            float parg = copysignf(m, s) - 10.0f;
            float p = ((cb >> (bo + j)) & 1) ? 0.f : __expf(parg);
            rsum[fn] += p;
            h4[j] = f16b(p);
          }
          uint2 u = { (unsigned)h4[0] | ((unsigned)h4[1] << 16),
                      (unsigned)h4[2] | ((unsigned)h4[3] << 16) };
          *(uint2*)(prow + n) = u;
        }
      }
    }
  }
#pragma unroll
  for (int fn = 0; fn < 4; ++fn) {
    rsum[fn] += __shfl_xor(rsum[fn], 16);
    rsum[fn] += __shfl_xor(rsum[fn], 32);
    int g = g0 + wg*64 + fn*16 + l15;
    if (lk == 0 && g < Gg) atomicAdd(rs + b*GP + g, rsum[fn]);
  }
}

// ---------------- normalize (XCD-matched): out = fp16 p * (1/rs) ----------
// grid 16384 = 8 xcd * (8 b * 256 inner); matches k_score's b->XCD mapping
// so po reads hit the writer XCD's L2.
__global__ __launch_bounds__(256) void k_norm(const float* __restrict__ ws,
                                              float* __restrict__ out) {
  int id = blockIdx.x, t = threadIdx.x;
  int xcd = id & 7, seq = id >> 3;            // seq in 0..2047
  int b = xcd * 8 + (seq >> 8);
  int inner = seq & 255;
  int v = inner * 256 + t;                    // 8-elem index within b
  if (v >= 62500) return;                     // 500 g * 125 cols
  int lg = v / 125;
  int n = (v - lg * 125) * 8;
  const unsigned short* po = (const unsigned short*)(ws + WS_PO);
  size_t bg = (size_t)b * Gg + lg;
  float inv = 1.0f / ws[WS_RS + b*GP + lg];
  uint4 u = *(const uint4*)(po + bg * 1024 + n);
  float* orow = out + bg * Nn + n;
  float4 o0, o1;
  o0.x = h2f((unsigned short)(u.x & 0xFFFF)) * inv;
  o0.y = h2f((unsigned short)(u.x >> 16)) * inv;
  o0.z = h2f((unsigned short)(u.y & 0xFFFF)) * inv;
  o0.w = h2f((unsigned short)(u.y >> 16)) * inv;
  o1.x = h2f((unsigned short)(u.z & 0xFFFF)) * inv;
  o1.y = h2f((unsigned short)(u.z >> 16)) * inv;
  o1.z = h2f((unsigned short)(u.w & 0xFFFF)) * inv;
  o1.w = h2f((unsigned short)(u.w >> 16)) * inv;
  *(float4*)orow = o0;
  *(float4*)(orow + 4) = o1;
}

extern "C" void kernel_launch(void* const* d_in, const int* in_sizes, int n_in,
                              void* d_out, int out_size, void* d_ws, size_t ws_size,
                              hipStream_t stream) {
  const float* emb       = (const float*)d_in[0];
  const float* dists     = (const float*)d_in[1];
  const int*   last_node = (const int*)d_in[2];
  const float* gm        = (const float*)d_in[3];
  const float* Wg        = (const float*)d_in[4];
  const float* Wf        = (const float*)d_in[5];
  const float* Wl        = (const float*)d_in[6];
  const float* Wv        = (const float*)d_in[7];
  float* out = (float*)d_out;
  float* ws  = (float*)d_ws;

  hipLaunchKernelGGL(k_front,  dim3(12672),     dim3(256), 0, stream, emb, gm, Wf, Wl, Wv, ws);
  hipLaunchKernelGGL(k_pool,   dim3(512),       dim3(256), 0, stream, ws);
  hipLaunchKernelGGL(k_finalq, dim3(512),       dim3(256), 0, stream, last_node, Wg, ws);
  hipLaunchKernelGGL(k_score,  dim3(2048),      dim3(256), 0, stream, dists, last_node, ws);
  hipLaunchKernelGGL(k_norm,   dim3(16384),     dim3(256), 0, stream, ws, out);
}